// Round 7
// baseline (625.620 us; speedup 1.0000x reference)
//
#include <hip/hip_runtime.h>
#include <math.h>

#define N_PTS 120000
#define D 256
#define BATCH 2
#define NH 8
#define DH 32
#define OUTC 20

#define Zd 60
#define Yd 45
#define Xd 4
#define Gq 10800
#define Sq 21600

#define Ze 12
#define Ye 24
#define Xe 2
#define Gk 576
#define Sk 1152

#define ATT_SCALE 0.17677669529663688f

typedef __bf16 bf16_t;
typedef __attribute__((ext_vector_type(8))) __bf16 bf16x8;
typedef __attribute__((ext_vector_type(4))) __bf16 bf16x4;
typedef __attribute__((ext_vector_type(4))) float f32x4;

// async global->LDS, 16B per lane; LDS dest is wave-uniform base + lane*16
__device__ __forceinline__ void glds16(const void* g, void* l) {
    __builtin_amdgcn_global_load_lds(
        (const __attribute__((address_space(1))) unsigned int*)g,
        (__attribute__((address_space(3))) unsigned int*)l,
        16, 0, 0);
}

// ---- weight prep: transpose + fp32->bf16; bias concat; Wseg transpose+pad ----
// Wqt/bqs are pre-scaled by ATT_SCALE so attention skips the per-score mul.
__global__ __launch_bounds__(256) void k_prep(
    const float* __restrict__ Wp, const float* __restrict__ We,
    const float* __restrict__ Wq, const float* __restrict__ Wk,
    const float* __restrict__ Wv, const float* __restrict__ Wo,
    const float* __restrict__ bp, const float* __restrict__ be,
    const float* __restrict__ bq, const float* __restrict__ bk,
    const float* __restrict__ bv,
    const float* __restrict__ Wseg, const float* __restrict__ bseg,
    bf16_t* __restrict__ Wpe, bf16_t* __restrict__ Wqt,
    bf16_t* __restrict__ Wkv, bf16_t* __restrict__ Wot,
    bf16_t* __restrict__ Wsegt,
    float* __restrict__ bpe, float* __restrict__ bkv,
    float* __restrict__ bsegp, float* __restrict__ bqs)
{
    int n = blockIdx.x, k = threadIdx.x;
    if (n < 512) {
        const float* S = (n < 256) ? Wp : We;
        int nn = n & 255;
        Wpe[n * 256 + k] = (bf16_t)S[k * 256 + nn];
    } else if (n < 768) {
        int nn = n - 512;
        Wqt[nn * 256 + k] = (bf16_t)(Wq[k * 256 + nn] * ATT_SCALE);
    } else if (n < 1280) {
        int m2 = n - 768;
        const float* S = (m2 < 256) ? Wk : Wv;
        int nn = m2 & 255;
        Wkv[m2 * 256 + k] = (bf16_t)S[k * 256 + nn];
    } else if (n < 1536) {
        int nn = n - 1280;
        Wot[nn * 256 + k] = (bf16_t)Wo[k * 256 + nn];
    } else if (n == 1536) {
        bpe[k] = bp[k]; bpe[256 + k] = be[k];
        bkv[k] = bk[k]; bkv[256 + k] = bv[k];
        bqs[k] = bq[k] * ATT_SCALE;
        if (k < 32) bsegp[k] = (k < OUTC) ? bseg[k] : 0.f;
    } else {
        int n2 = n - 1537;   // 0..31
        Wsegt[n2 * 256 + k] = (n2 < OUTC) ? (bf16_t)Wseg[k * OUTC + n2] : (bf16_t)0.f;
    }
}

// ---- features fp32 -> bf16 copy (streaming, 8 elems/thread/iter) ----
__global__ __launch_bounds__(256) void k_cast(
    const float* __restrict__ in, bf16_t* __restrict__ out)
{
    const size_t total = (size_t)N_PTS * 32;   // groups of 8 floats
    const size_t stride = (size_t)gridDim.x * 256;
    for (size_t i = (size_t)blockIdx.x * 256 + threadIdx.x; i < total; i += stride) {
        float4 a = *(const float4*)(in + i * 8);
        float4 b = *(const float4*)(in + i * 8 + 4);
        bf16x8 o;
        o[0] = (bf16_t)a.x; o[1] = (bf16_t)a.y; o[2] = (bf16_t)a.z; o[3] = (bf16_t)a.w;
        o[4] = (bf16_t)b.x; o[5] = (bf16_t)b.y; o[6] = (bf16_t)b.z; o[7] = (bf16_t)b.w;
        *(bf16x8*)(out + i * 8) = o;
    }
}

// ---- CSR build: histogram -> scan -> placement ----
__global__ __launch_bounds__(256) void k_count(
    const int* __restrict__ indices, int* __restrict__ cnt_q, int* __restrict__ cnt_k,
    int* __restrict__ segq, int* __restrict__ segk)
{
    int i = blockIdx.x * 256 + threadIdx.x;
    if (i >= N_PTS) return;
    const int* id = indices + (size_t)i * 4;
    int b = id[0], z = id[1], y = id[2], x = id[3];
    int sq = ((b * Zd + (z >> 3)) * Yd + (y >> 3)) * Xd + (x >> 3);
    int sk = ((b * Ze + (z / 40)) * Ye + (y / 15)) * Xe + (x >> 4);
    segq[i] = sq; segk[i] = sk;
    atomicAdd(&cnt_q[sq], 1);
    atomicAdd(&cnt_k[sk], 1);
}

// single-block exclusive scan (wave shfl scan + cross-wave LDS)
__global__ __launch_bounds__(1024) void k_scan(
    const int* __restrict__ cnt, int n, int* __restrict__ offs, int* __restrict__ cursor)
{
    __shared__ int wbase[17];
    __shared__ int carry_s;
    const int t = threadIdx.x, lane = t & 63, w = t >> 6;
    if (t == 0) carry_s = 0;
    __syncthreads();
    for (int base = 0; base < n; base += 1024) {
        int v = (base + t < n) ? cnt[base + t] : 0;
        int incl = v;
        #pragma unroll
        for (int off = 1; off < 64; off <<= 1) {
            int u = __shfl_up(incl, off);
            if (lane >= off) incl += u;
        }
        if (lane == 63) wbase[w + 1] = incl;
        __syncthreads();
        if (t == 0) {
            int s = 0;
            wbase[0] = 0;
            #pragma unroll
            for (int i = 1; i <= 16; ++i) { s += wbase[i]; wbase[i] = s; }
        }
        __syncthreads();
        int excl = incl - v + wbase[w] + carry_s;
        if (base + t < n) { offs[base + t] = excl; cursor[base + t] = excl; }
        __syncthreads();
        if (t == 0) carry_s += wbase[16];
        __syncthreads();
    }
}

__global__ __launch_bounds__(256) void k_place(
    const int* __restrict__ segq, const int* __restrict__ segk,
    int* __restrict__ cur_q, int* __restrict__ cur_k,
    int* __restrict__ ids_q, int* __restrict__ ids_k)
{
    int i = blockIdx.x * 256 + threadIdx.x;
    if (i >= N_PTS) return;
    ids_q[atomicAdd(&cur_q[segq[i]], 1)] = i;
    ids_k[atomicAdd(&cur_k[segk[i]], 1)] = i;
}

// ---- fast MFMA GEMM, bf16 A: [M x 256] bf16 @ Wt[128-col tile x 256] bf16 ----
__global__ __launch_bounds__(256, 4) void k_gemm_bf(
    const bf16_t* __restrict__ A, int M,
    const bf16_t* __restrict__ Wt, const float* __restrict__ bias,
    bf16_t* __restrict__ outb, int ldo)
{
    __shared__ __align__(16) bf16_t Abuf[128 * 64];
    __shared__ __align__(16) bf16_t Bbuf[128 * 64];

    const int t = threadIdx.x;
    const int wave = t >> 6, lane = t & 63;
    const int wr = wave >> 1, wc = wave & 1;
    const int lrow = lane & 15, quad = lane >> 4;
    const int lr8 = lane >> 3, lc8 = lane & 7;
    const int row0 = blockIdx.y * 128;
    const int ntile = blockIdx.x;

    f32x4 acc[4][4];
    #pragma unroll
    for (int mi = 0; mi < 4; ++mi)
        #pragma unroll
        for (int ni = 0; ni < 4; ++ni)
            acc[mi][ni] = (f32x4){0.f, 0.f, 0.f, 0.f};

    for (int k0 = 0; k0 < 256; k0 += 64) {
        #pragma unroll
        for (int i = 0; i < 4; ++i) {
            int chunk = wave * 4 + i;
            int rowA = row0 + chunk * 8 + lr8;
            if (rowA > M - 1) rowA = M - 1;       // clamp, masked at write
            glds16(A + (size_t)rowA * 256 + k0 + lc8 * 8, &Abuf[chunk * 512]);
        }
        #pragma unroll
        for (int i = 0; i < 4; ++i) {
            int chunk = wave * 4 + i;
            glds16(Wt + (size_t)(ntile * 128 + chunk * 8 + lr8) * 256 + k0 + lc8 * 8,
                   &Bbuf[chunk * 512]);
        }
        asm volatile("s_waitcnt vmcnt(0)" ::: "memory");
        __builtin_amdgcn_sched_barrier(0);
        __syncthreads();

        #pragma unroll
        for (int kk = 0; kk < 64; kk += 32) {
            bf16x8 Af[4], Bf[4];
            #pragma unroll
            for (int mi = 0; mi < 4; ++mi)
                Af[mi] = *(const bf16x8*)&Abuf[(wr * 64 + mi * 16 + lrow) * 64 + kk + quad * 8];
            #pragma unroll
            for (int ni = 0; ni < 4; ++ni)
                Bf[ni] = *(const bf16x8*)&Bbuf[(wc * 64 + ni * 16 + lrow) * 64 + kk + quad * 8];
            #pragma unroll
            for (int mi = 0; mi < 4; ++mi)
                #pragma unroll
                for (int ni = 0; ni < 4; ++ni)
                    acc[mi][ni] = __builtin_amdgcn_mfma_f32_16x16x32_bf16(
                        Af[mi], Bf[ni], acc[mi][ni], 0, 0, 0);
        }
        __syncthreads();
    }

    const int colb = ntile * 128 + wc * 64;
    float biasv[4];
    #pragma unroll
    for (int ni = 0; ni < 4; ++ni) biasv[ni] = bias[colb + ni * 16 + lrow];

    #pragma unroll
    for (int mi = 0; mi < 4; ++mi) {
        int lr = wr * 64 + mi * 16 + quad * 4;
        #pragma unroll
        for (int reg = 0; reg < 4; ++reg) {
            int grow = row0 + lr + reg;
            if (grow >= M) continue;
            #pragma unroll
            for (int ni = 0; ni < 4; ++ni) {
                int col = colb + ni * 16 + lrow;
                outb[(size_t)grow * ldo + col] = (bf16_t)(acc[mi][ni][reg] + biasv[ni]);
            }
        }
    }
}

// ---- MFMA GEMM (fp32 A, VALU staging): mode 0 fp32 out; mode 2 bf16 out ----
__global__ __launch_bounds__(512, 2) void k_gemm(
    const float* __restrict__ A, int M,
    const bf16_t* __restrict__ Wt, const float* __restrict__ bias,
    int mode, float* __restrict__ outp, int ldo)
{
    __shared__ __align__(16) bf16_t Abuf[128][72];
    __shared__ __align__(16) bf16_t Bbuf[256][72];

    const int t = threadIdx.x;
    const int wave = t >> 6, lane = t & 63;
    const int wr = wave >> 2, wc = wave & 3;
    const int lrow = lane & 15, quad = lane >> 4;
    const int row0 = blockIdx.y * 128;
    const int ntile = blockIdx.x;

    f32x4 acc[4][4];
    #pragma unroll
    for (int mi = 0; mi < 4; ++mi)
        #pragma unroll
        for (int ni = 0; ni < 4; ++ni)
            acc[mi][ni] = (f32x4){0.f, 0.f, 0.f, 0.f};

    for (int k0 = 0; k0 < 256; k0 += 64) {
        #pragma unroll
        for (int i = 0; i < 4; ++i) {
            int c = i * 512 + t;
            int r = c >> 4, c4 = c & 15;
            float4 v = make_float4(0.f, 0.f, 0.f, 0.f);
            if (row0 + r < M)
                v = *(const float4*)(A + (size_t)(row0 + r) * 256 + k0 + c4 * 4);
            bf16x4 bv4;
            bv4[0] = (bf16_t)v.x; bv4[1] = (bf16_t)v.y;
            bv4[2] = (bf16_t)v.z; bv4[3] = (bf16_t)v.w;
            *(bf16x4*)&Abuf[r][c4 * 4] = bv4;
        }
        #pragma unroll
        for (int i = 0; i < 4; ++i) {
            int c = i * 512 + t;
            int r = c >> 3, c8 = c & 7;
            uint4 w = *(const uint4*)(Wt + ((size_t)(ntile * 256 + r)) * 256 + k0 + c8 * 8);
            *(uint4*)&Bbuf[r][c8 * 8] = w;
        }
        __syncthreads();

        #pragma unroll
        for (int kk = 0; kk < 64; kk += 32) {
            bf16x8 Af[4], Bf[4];
            #pragma unroll
            for (int mi = 0; mi < 4; ++mi)
                Af[mi] = *(const bf16x8*)&Abuf[wr * 64 + mi * 16 + lrow][kk + quad * 8];
            #pragma unroll
            for (int ni = 0; ni < 4; ++ni)
                Bf[ni] = *(const bf16x8*)&Bbuf[wc * 64 + ni * 16 + lrow][kk + quad * 8];
            #pragma unroll
            for (int mi = 0; mi < 4; ++mi)
                #pragma unroll
                for (int ni = 0; ni < 4; ++ni)
                    acc[mi][ni] = __builtin_amdgcn_mfma_f32_16x16x32_bf16(
                        Af[mi], Bf[ni], acc[mi][ni], 0, 0, 0);
        }
        __syncthreads();
    }

    const int colb = ntile * 256 + wc * 64;
    float biasv[4];
    #pragma unroll
    for (int ni = 0; ni < 4; ++ni) biasv[ni] = bias[colb + ni * 16 + lrow];

    if (mode == 0) {
        #pragma unroll
        for (int mi = 0; mi < 4; ++mi) {
            int lr = wr * 64 + mi * 16 + quad * 4;
            #pragma unroll
            for (int reg = 0; reg < 4; ++reg) {
                int grow = row0 + lr + reg;
                if (grow >= M) continue;
                #pragma unroll
                for (int ni = 0; ni < 4; ++ni) {
                    int col = colb + ni * 16 + lrow;
                    outp[(size_t)grow * ldo + col] = acc[mi][ni][reg] + biasv[ni];
                }
            }
        }
    } else {
        bf16_t* outb = (bf16_t*)outp;
        #pragma unroll
        for (int mi = 0; mi < 4; ++mi) {
            int lr = wr * 64 + mi * 16 + quad * 4;
            #pragma unroll
            for (int reg = 0; reg < 4; ++reg) {
                int grow = row0 + lr + reg;
                if (grow >= M) continue;
                #pragma unroll
                for (int ni = 0; ni < 4; ++ni) {
                    int col = colb + ni * 16 + lrow;
                    outb[(size_t)grow * ldo + col] = (bf16_t)(acc[mi][ni][reg] + biasv[ni]);
                }
            }
        }
    }
}

// ---- sine PE helper ----
__device__ inline float pe_val(int j, float cz, float cy, float cx) {
    if (j >= 252) return 0.f;
    int dim = j / 84;
    int f = j % 84;
    int fi = (f >= 42) ? (f - 42) : f;
    float c  = (dim == 0) ? cz : ((dim == 1) ? cy : cx);
    float sp = (dim == 0) ? 480.f : ((dim == 1) ? 360.f : 32.f);
    float cn = c / sp * 6.28318530717958647692f;
    float tt = expf((float)fi * (9.210340371976184f / 42.f));
    float ang = cn / tt;
    return (f >= 42) ? cosf(ang) : sinf(ang);
}

// ---- pool branch segment-max: one wave per segment (~5.6 pts/seg), PE fused ----
__global__ __launch_bounds__(256) void k_pool_q(
    const bf16_t* __restrict__ pfb, const int* __restrict__ ids,
    const int* __restrict__ offs, const int* __restrict__ cnt,
    float* __restrict__ out)
{
    const int t = threadIdx.x, lane = t & 63, w = t >> 6;
    const int s = blockIdx.x * 4 + w;
    if (s >= Sq) return;
    const int count = cnt[s], start = offs[s];
    float mx[4] = {-3.0e38f, -3.0e38f, -3.0e38f, -3.0e38f};
    for (int r = 0; r < count; ++r) {
        int i = ids[start + r];
        bf16x4 v = *(const bf16x4*)(pfb + (size_t)i * 256 + lane * 4);
        #pragma unroll
        for (int j = 0; j < 4; ++j) mx[j] = fmaxf(mx[j], (float)v[j]);
    }
    int rem = s % Gq;
    float cz = (float)((rem / (Yd * Xd)) * 8);
    float cy = (float)(((rem / Xd) % Yd) * 8);
    float cx = (float)((rem % Xd) * 8);
    #pragma unroll
    for (int j = 0; j < 4; ++j) {
        float v = (count > 0) ? mx[j] : 0.f;
        out[(size_t)s * 256 + lane * 4 + j] = v + pe_val(lane * 4 + j, cz, cy, cx);
    }
}

// ---- emb branch segment-max: one block (8 waves) per segment (~104 pts/seg) ----
__global__ __launch_bounds__(512) void k_pool_k(
    const bf16_t* __restrict__ efb, const int* __restrict__ ids,
    const int* __restrict__ offs, const int* __restrict__ cnt,
    float* __restrict__ out, int* __restrict__ kmask)
{
    __shared__ float red[8][256];
    const int t = threadIdx.x, lane = t & 63, w = t >> 6;
    const int s = blockIdx.x;
    const int count = cnt[s], start = offs[s];
    float mx[4] = {-3.0e38f, -3.0e38f, -3.0e38f, -3.0e38f};
    for (int r = w; r < count; r += 8) {
        int i = ids[start + r];
        bf16x4 v = *(const bf16x4*)(efb + (size_t)i * 256 + lane * 4);
        #pragma unroll
        for (int j = 0; j < 4; ++j) mx[j] = fmaxf(mx[j], (float)v[j]);
    }
    #pragma unroll
    for (int j = 0; j < 4; ++j) red[w][lane * 4 + j] = mx[j];
    __syncthreads();
    if (t < 256) {
        float m = red[0][t];
        #pragma unroll
        for (int i = 1; i < 8; ++i) m = fmaxf(m, red[i][t]);
        if (count == 0) m = 0.f;
        int rem = s % Gk;
        float cz = (float)((rem / (Ye * Xe)) * 40);
        float cy = (float)(((rem / Xe) % Ye) * 15);
        float cx = (float)((rem % Xe) * 16);
        out[(size_t)s * 256 + t] = m + pe_val(t, cz, cy, cx);
        if (t == 0) kmask[s] = (count > 0) ? 1 : 0;
    }
}

// ---- V transpose: VT[bh][d][g] = KVb[(b*Gk+g)*512 + 256 + h*32 + d] ----
__global__ __launch_bounds__(256) void k_vt(
    const bf16_t* __restrict__ KVb, bf16_t* __restrict__ VT)
{
    int idx = blockIdx.x * 256 + threadIdx.x;   // over 16*32*576 = 294912
    if (idx >= 16 * 32 * 576) return;
    int g = idx % 576;
    int d = (idx / 576) & 31;
    int bh = idx / (576 * 32);
    int b = bh >> 3, h = bh & 7;
    VT[idx] = KVb[((size_t)(b * Gk + g)) * 512 + 256 + h * 32 + d];
}

// ---- MFMA flash attention v4: two-pass softmax (Gk small), no online rescale ----
// 768 thr (12 waves), 192 Q-rows/block. Pass 1: QK^T stream -> row max.
// Pass 2: QK^T again, p=exp(s-m), PV per 96-key chunk. One shfl-reduce per pass.
__global__ __launch_bounds__(768, 6) void k_attn4(
    const bf16_t* __restrict__ Q, const bf16_t* __restrict__ KV,
    const bf16_t* __restrict__ VT, const int* __restrict__ kmask,
    float* __restrict__ O)
{
    __shared__ __align__(16) bf16_t Vts[32][584];    // 37376 B
    __shared__ __align__(16) bf16_t Ps[12][16][104]; // 39936 B
    __shared__ float mskf[576];                      //  2304 B (total ~79.6 KB)

    const int bh = blockIdx.y;
    const int b = bh >> 3, h = bh & 7;
    const int t = threadIdx.x, wave = t >> 6, lane = t & 63;
    const int lrow = lane & 15, quad = lane >> 4;
    const int q0 = blockIdx.x * 192;

    // stage VT: 32 rows x 72 uint4 = 2304
    #pragma unroll
    for (int i = 0; i < 3; ++i) {
        int id = i * 768 + t;
        int d = id / 72, c8 = id % 72;
        uint4 v = *(const uint4*)(VT + (size_t)(bh * 32 + d) * 576 + c8 * 8);
        *(uint4*)&Vts[d][c8 * 8] = v;
    }
    if (t < 576)
        mskf[t] = kmask[b * Gk + t] ? 0.f : -1.0e9f;
    __syncthreads();

    // per-lane Q fragment (A operand)
    int qa = q0 + wave * 16 + lrow;
    if (qa > Gq - 1) qa = Gq - 1;
    const bf16x8 Aq = *(const bf16x8*)(Q + ((size_t)(b * Gq + qa)) * 256 + h * 32 + quad * 8);

    const bf16_t* Kbase = KV + ((size_t)b * Gk) * 512 + h * 32;

    // ---- pass 1: global row max (no cross-lane ops in the loop) ----
    float m[4] = {-3.0e38f, -3.0e38f, -3.0e38f, -3.0e38f};
    #pragma unroll 4
    for (int kt = 0; kt < 36; ++kt) {
        bf16x8 Bk = *(const bf16x8*)(Kbase + (size_t)(kt * 16 + lrow) * 512 + quad * 8);
        f32x4 sacc = __builtin_amdgcn_mfma_f32_16x16x32_bf16(
            Aq, Bk, (f32x4){0.f, 0.f, 0.f, 0.f}, 0, 0, 0);
        float pen = mskf[kt * 16 + lrow];
        #pragma unroll
        for (int r = 0; r < 4; ++r) m[r] = fmaxf(m[r], sacc[r] + pen);
    }
    #pragma unroll
    for (int r = 0; r < 4; ++r)
        #pragma unroll
        for (int off = 1; off < 16; off <<= 1)
            m[r] = fmaxf(m[r], __shfl_xor(m[r], off));

    // ---- pass 2: exp + PV ----
    f32x4 oacc[2];
    oacc[0] = (f32x4){0.f, 0.f, 0.f, 0.f};
    oacc[1] = (f32x4){0.f, 0.f, 0.f, 0.f};
    float l[4] = {0.f, 0.f, 0.f, 0.f};

    for (int c0 = 0; c0 < Gk; c0 += 96) {
        #pragma unroll
        for (int nt = 0; nt < 6; ++nt) {
            bf16x8 Bk = *(const bf16x8*)(Kbase + (size_t)(c0 + nt * 16 + lrow) * 512 + quad * 8);
            f32x4 sacc = __builtin_amdgcn_mfma_f32_16x16x32_bf16(
                Aq, Bk, (f32x4){0.f, 0.f, 0.f, 0.f}, 0, 0, 0);
            float pen = mskf[c0 + nt * 16 + lrow];
            #pragma unroll
            for (int r = 0; r < 4; ++r) {
                float p = __expf(sacc[r] + pen - m[r]);
                l[r] += p;
                Ps[wave][quad * 4 + r][nt * 16 + lrow] = (bf16_t)p;
            }
        }
        #pragma unroll
        for (int ks = 0; ks < 3; ++ks) {
            bf16x8 Ap = *(const bf16x8*)&Ps[wave][lrow][ks * 32 + quad * 8];
            #pragma unroll
            for (int n2 = 0; n2 < 2; ++n2) {
                bf16x8 Bv = *(const bf16x8*)&Vts[n2 * 16 + lrow][c0 + ks * 32 + quad * 8];
                oacc[n2] = __builtin_amdgcn_mfma_f32_16x16x32_bf16(
                    Ap, Bv, oacc[n2], 0, 0, 0);
            }
        }
    }

    #pragma unroll
    for (int r = 0; r < 4; ++r)
        #pragma unroll
        for (int off = 1; off < 16; off <<= 1)
            l[r] += __shfl_xor(l[r], off);

    #pragma unroll
    for (int r = 0; r < 4; ++r) {
        int qi = q0 + wave * 16 + quad * 4 + r;
        if (qi >= Gq) continue;
        float inv = (l[r] > 0.f) ? (1.f / l[r]) : 0.f;
        #pragma unroll
        for (int n2 = 0; n2 < 2; ++n2)
            O[((size_t)(b * Gq + qi)) * 256 + h * 32 + n2 * 16 + lrow] = oacc[n2][r] * inv;
    }
}

// ---- residual + LayerNorm ----
__global__ __launch_bounds__(256) void k_ln(
    const float* __restrict__ oproj, const float* __restrict__ resid,
    const float* __restrict__ g, const float* __restrict__ bta,
    float* __restrict__ out)
{
    const int s = blockIdx.x, t = threadIdx.x;
    float h = resid[(size_t)s * D + t] + oproj[(size_t)s * D + t];

    float s1 = h, s2 = h * h;
    for (int o = 32; o > 0; o >>= 1) {
        s1 += __shfl_down(s1, o);
        s2 += __shfl_down(s2, o);
    }
    __shared__ float r1[4], r2[4];
    __shared__ float mu_s, rstd_s;
    int w = t >> 6;
    if ((t & 63) == 0) { r1[w] = s1; r2[w] = s2; }
    __syncthreads();
    if (t == 0) {
        float a = r1[0] + r1[1] + r1[2] + r1[3];
        float bsum = r2[0] + r2[1] + r2[2] + r2[3];
        float mu = a * (1.f / 256.f);
        float var = bsum * (1.f / 256.f) - mu * mu;
        mu_s = mu;
        rstd_s = rsqrtf(var + 1e-5f);
    }
    __syncthreads();
    out[(size_t)s * D + t] = (h - mu_s) * rstd_s * g[t] + bta[t];
}

// ---- final: vox = feat + mhca[seg_q]; logits = vox @ Wsegt^T + bseg via MFMA ----
// featb (bf16 copy) used when non-null (halves feature fetch bytes).
__global__ __launch_bounds__(512, 2) void k_logits_mfma(
    const float* __restrict__ feat, const bf16_t* __restrict__ featb,
    const float* __restrict__ mhca,
    const int* __restrict__ indices, const bf16_t* __restrict__ Wsegt,
    const float* __restrict__ bsegp, float* __restrict__ out)
{
    __shared__ __align__(16) bf16_t Abuf[128][72];
    __shared__ __align__(16) bf16_t Bbuf[32][72];
    __shared__ int sq_s[128];

    const int t = threadIdx.x;
    const int wave = t >> 6, lane = t & 63;
    const int lrow = lane & 15, quad = lane >> 4;
    const int row0 = blockIdx.x * 128;

    if (t < 128) {
        int row = row0 + t;
        if (row < N_PTS) {
            const int* id = indices + (size_t)row * 4;
            sq_s[t] = ((id[0] * Zd + (id[1] >> 3)) * Yd + (id[2] >> 3)) * Xd + (id[3] >> 3);
        } else sq_s[t] = 0;
    }
    __syncthreads();

    f32x4 acc[2];
    acc[0] = (f32x4){0.f, 0.f, 0.f, 0.f};
    acc[1] = (f32x4){0.f, 0.f, 0.f, 0.f};

    for (int k0 = 0; k0 < 256; k0 += 64) {
        #pragma unroll
        for (int i = 0; i < 4; ++i) {
            int c = i * 512 + t;
            int r = c >> 4, c4 = c & 15;
            float4 v = make_float4(0.f, 0.f, 0.f, 0.f);
            int grow = row0 + r;
            if (grow < N_PTS) {
                float4 mm = *(const float4*)(mhca + (size_t)sq_s[r] * 256 + k0 + c4 * 4);
                if (featb) {
                    bf16x4 fv = *(const bf16x4*)(featb + (size_t)grow * 256 + k0 + c4 * 4);
                    v.x = (float)fv[0] + mm.x; v.y = (float)fv[1] + mm.y;
                    v.z = (float)fv[2] + mm.z; v.w = (float)fv[3] + mm.w;
                } else {
                    v = *(const float4*)(feat + (size_t)grow * 256 + k0 + c4 * 4);
                    v.x += mm.x; v.y += mm.y; v.z += mm.z; v.w += mm.w;
                }
            }
            bf16x4 bv4;
            bv4[0] = (bf16_t)v.x; bv4[1] = (bf16_t)v.y;
            bv4[2] = (bf16_t)v.z; bv4[3] = (bf16_t)v.w;
            *(bf16x4*)&Abuf[r][c4 * 4] = bv4;
        }
        if (t < 256) {
            int r = t >> 3, c8 = t & 7;
            uint4 w = *(const uint4*)(Wsegt + (size_t)r * 256 + k0 + c8 * 8);
            *(uint4*)&Bbuf[r][c8 * 8] = w;
        }
        __syncthreads();

        #pragma unroll
        for (int kk = 0; kk < 64; kk += 32) {
            bf16x8 Af = *(const bf16x8*)&Abuf[wave * 16 + lrow][kk + quad * 8];
            #pragma unroll
            for (int ni = 0; ni < 2; ++ni) {
                bf16x8 Bf = *(const bf16x8*)&Bbuf[ni * 16 + lrow][kk + quad * 8];
                acc[ni] = __builtin_amdgcn_mfma_f32_16x16x32_bf16(
                    Af, Bf, acc[ni], 0, 0, 0);
            }
        }
        __syncthreads();
    }

    #pragma unroll
    for (int ni = 0; ni < 2; ++ni) {
        int col = ni * 16 + lrow;
        if (col >= OUTC) continue;
        float bias = bsegp[col];
        #pragma unroll
        for (int reg = 0; reg < 4; ++reg) {
            int grow = row0 + wave * 16 + quad * 4 + reg;
            if (grow >= N_PTS) continue;
            out[(size_t)grow * OUTC + col] = acc[ni][reg] + bias;
        }
    }
}

extern "C" void kernel_launch(void* const* d_in, const int* in_sizes, int n_in,
                              void* d_out, int out_size, void* d_ws, size_t ws_size,
                              hipStream_t stream) {
    const float* features = (const float*)d_in[0];
    const float* W_pool = (const float*)d_in[1];
    const float* b_pool = (const float*)d_in[2];
    const float* W_emb  = (const float*)d_in[3];
    const float* b_emb  = (const float*)d_in[4];
    const float* Wq = (const float*)d_in[5];
    const float* bq = (const float*)d_in[6];
    const float* Wk = (const float*)d_in[7];
    const float* bk = (const float*)d_in[8];
    const float* Wv = (const float*)d_in[9];
    const float* bv = (const float*)d_in[10];
    const float* Wo = (const float*)d_in[11];
    const float* bo = (const float*)d_in[12];
    const float* ln_g = (const float*)d_in[13];
    const float* ln_b = (const float*)d_in[14];
    const float* W_seg = (const float*)d_in[15];
    const float* b_seg = (const float*)d_in[16];
    const int* indices = (const int*)d_in[17];
    float* out = (float*)d_out;

    float* ws = (float*)d_ws;
    const size_t SQD = (size_t)Sq * D;           // 5,529,600
    const size_t SKD = (size_t)Sk * D;           // 294,912
    const size_t PFB_FL = (size_t)N_PTS * D / 2; // 15,360,000 float slots (bf16 [N][256])

    // region P: pfb/efb (bf16) -> later Qb/KVb/attnO/oproj/mhca
    size_t oP   = 0;
    size_t oPF  = oP + PFB_FL;       // pool_feat fp32 [Sq][256]
    size_t oEF  = oPF + SQD;         // emb_feat fp32 [Sk][256]; later VT bf16 [16][32][576]
    size_t oWpe = oEF + SKD;         // 65536
    size_t oWqt = oWpe + 65536;      // 32768
    size_t oWkv = oWqt + 32768;      // 65536
    size_t oWot = oWkv + 65536;      // 32768
    size_t obpe = oWot + 32768;      // 512
    size_t obkv = obpe + 512;        // 512
    size_t oCnt = obkv + 512;        // cnt_q 21600 + cnt_k 1152 (zeroed)
    size_t oOffq = oCnt + 21600 + 1152;
    size_t oCurq = oOffq + 21600;
    size_t oOffk = oCurq + 21600;
    size_t oCurk = oOffk + 1152;
    size_t oSegq = oCurk + 1152;
    size_t oSegk = oSegq + N_PTS;
    size_t oIdsq = oSegk + N_PTS;
    size_t oIdsk = oIdsq + N_PTS;
    size_t oKm   = oIdsk + N_PTS;    // kmask 1152 ints
    size_t oWst  = oKm + 1152;       // Wsegt bf16 [32][256] = 4096 floats
    size_t obsg  = oWst + 4096;      // bsegp [32]
    size_t obqs  = obsg + 32;        // bqs [256] (scaled bq)
    size_t oFB   = obqs + 256;       // fb16 bf16 [N][256] (optional fast path)

    bf16_t* pfb = (bf16_t*)(ws + oP);
    float* pool_feat = ws + oPF;
    float* emb_feat  = ws + oEF;
    bf16_t* Wpe = (bf16_t*)(ws + oWpe);
    bf16_t* Wqt = (bf16_t*)(ws + oWqt);
    bf16_t* Wkv = (bf16_t*)(ws + oWkv);
    bf16_t* Wot = (bf16_t*)(ws + oWot);
    float* bpe = ws + obpe;
    float* bkv = ws + obkv;
    int* cnt_q = (int*)(ws + oCnt);
    int* cnt_k = cnt_q + 21600;
    int* offs_q = (int*)(ws + oOffq);
    int* cur_q  = (int*)(ws + oCurq);
    int* offs_k = (int*)(ws + oOffk);
    int* cur_k  = (int*)(ws + oCurk);
    int* segq = (int*)(ws + oSegq);
    int* segk = (int*)(ws + oSegk);
    int* ids_q = (int*)(ws + oIdsq);
    int* ids_k = (int*)(ws + oIdsk);
    int* kmask = (int*)(ws + oKm);
    bf16_t* Wsegt = (bf16_t*)(ws + oWst);
    float* bsegp = ws + obsg;
    float* bqs = ws + obqs;
    bf16_t* fb16 = (bf16_t*)(ws + oFB);

    // aliases inside region P (pfb dead after pooling kernels)
    bf16_t* Qb  = (bf16_t*)(ws + oP);
    bf16_t* KVb = (bf16_t*)(ws + oP + 2764800);
    float* attnO = ws + oP + 3059712;
    float* oproj = ws + oP + 8589312;
    float* mhca  = ws + oP + 3059712;   // reuses attnO slot after oproj gemm
    // VT reuses the emb_feat slot (emb_feat dead after the KV gemm)
    bf16_t* VT = (bf16_t*)(ws + oEF);

    const bool fast = ws_size >= (oFB + PFB_FL) * sizeof(float);

    // zero only the two histograms (~91 KB)
    hipMemsetAsync(cnt_q, 0, (21600 + 1152) * sizeof(int), stream);

    k_prep<<<1569, 256, 0, stream>>>(W_pool, W_emb, Wq, Wk, Wv, Wo,
                                     b_pool, b_emb, bq, bk, bv, W_seg, b_seg,
                                     Wpe, Wqt, Wkv, Wot, Wsegt, bpe, bkv, bsegp, bqs);

    if (fast)
        k_cast<<<2048, 256, 0, stream>>>(features, fb16);

    // CSR build
    k_count<<<(N_PTS + 255) / 256, 256, 0, stream>>>(indices, cnt_q, cnt_k, segq, segk);
    k_scan<<<1, 1024, 0, stream>>>(cnt_q, 21600, offs_q, cur_q);
    k_scan<<<1, 1024, 0, stream>>>(cnt_k, 1152, offs_k, cur_k);
    k_place<<<(N_PTS + 255) / 256, 256, 0, stream>>>(segq, segk, cur_q, cur_k, ids_q, ids_k);

    // --- emb branch: ef = features @ W_emb + b_emb (bf16), then gather-max ---
    if (fast) {
        dim3 g(2, (N_PTS + 127) / 128);
        k_gemm_bf<<<g, 256, 0, stream>>>(fb16, N_PTS, Wpe + 256 * 256, bpe + 256,
                                         pfb, 256);
    } else {
        dim3 g(1, (N_PTS + 127) / 128);
        k_gemm<<<g, 512, 0, stream>>>(features, N_PTS, Wpe + 256 * 256, bpe + 256, 2,
                                      (float*)pfb, 256);
    }
    k_pool_k<<<Sk, 512, 0, stream>>>(pfb, ids_k, offs_k, cnt_k, emb_feat, kmask);

    // --- pool branch: pf = features @ W_pool + b_pool (bf16), then gather-max ---
    if (fast) {
        dim3 g(2, (N_PTS + 127) / 128);
        k_gemm_bf<<<g, 256, 0, stream>>>(fb16, N_PTS, Wpe, bpe, pfb, 256);
    } else {
        dim3 g(1, (N_PTS + 127) / 128);
        k_gemm<<<g, 512, 0, stream>>>(features, N_PTS, Wpe, bpe, 2,
                                      (float*)pfb, 256);
    }
    k_pool_q<<<(Sq + 3) / 4, 256, 0, stream>>>(pfb, ids_q, offs_q, cnt_q, pool_feat);

    // Q = pool_feat @ (Wq*s) + bq*s  (bf16 out; attention scale pre-folded)
    {
        dim3 g(1, (Sq + 127) / 128);
        k_gemm<<<g, 512, 0, stream>>>(pool_feat, Sq, Wqt, bqs, 2, (float*)Qb, 256);
    }
    // KV = emb_feat @ [Wk|Wv] + [bk|bv], interleaved bf16 [Sk][512]
    {
        dim3 g(2, (Sk + 127) / 128);
        k_gemm<<<g, 512, 0, stream>>>(emb_feat, Sk, Wkv, bkv, 2, (float*)KVb, 512);
    }

    // V pre-transpose (emb_feat is dead now; VT aliases it)
    k_vt<<<(16 * 32 * 576 + 255) / 256, 256, 0, stream>>>(KVb, VT);

    {
        dim3 ag((Gq + 191) / 192, BATCH * NH);
        k_attn4<<<ag, 768, 0, stream>>>(Qb, KVb, VT, kmask, attnO);
    }

    // oproj = attnO @ Wo + bo (fp32 out)
    {
        dim3 g(1, (Sq + 127) / 128);
        k_gemm<<<g, 512, 0, stream>>>(attnO, Sq, Wot, bo, 0, oproj, 256);
    }

    k_ln<<<Sq, 256, 0, stream>>>(oproj, pool_feat, ln_g, ln_b, mhca);

    k_logits_mfma<<<(N_PTS + 127) / 128, 512, 0, stream>>>(
        features, fast ? fb16 : (const bf16_t*)nullptr, mhca, indices, Wsegt, bsegp, out);
}

// Round 8
// 574.972 us; speedup vs baseline: 1.0881x; 1.0881x over previous
//
#include <hip/hip_runtime.h>
#include <math.h>

#define N_PTS 120000
#define D 256
#define BATCH 2
#define NH 8
#define DH 32
#define OUTC 20

#define Zd 60
#define Yd 45
#define Xd 4
#define Gq 10800
#define Sq 21600

#define Ze 12
#define Ye 24
#define Xe 2
#define Gk 576
#define Sk 1152

// 1/sqrt(32) * log2(e): attention scale with exp2 base-change pre-folded
#define QK_SCALE (0.17677669529663688f * 1.4426950408889634f)

typedef __bf16 bf16_t;
typedef __attribute__((ext_vector_type(8))) __bf16 bf16x8;
typedef __attribute__((ext_vector_type(4))) __bf16 bf16x4;
typedef __attribute__((ext_vector_type(4))) float f32x4;

// async global->LDS, 16B per lane; LDS dest is wave-uniform base + lane*16
__device__ __forceinline__ void glds16(const void* g, void* l) {
    __builtin_amdgcn_global_load_lds(
        (const __attribute__((address_space(1))) unsigned int*)g,
        (__attribute__((address_space(3))) unsigned int*)l,
        16, 0, 0);
}

// ---- weight prep: transpose + fp32->bf16; bias concat; Wseg transpose+pad ----
// Wqt/bqs are pre-scaled by QK_SCALE (1/sqrt(dh) * log2e) for exp2 softmax.
__global__ __launch_bounds__(256) void k_prep(
    const float* __restrict__ Wp, const float* __restrict__ We,
    const float* __restrict__ Wq, const float* __restrict__ Wk,
    const float* __restrict__ Wv, const float* __restrict__ Wo,
    const float* __restrict__ bp, const float* __restrict__ be,
    const float* __restrict__ bq, const float* __restrict__ bk,
    const float* __restrict__ bv,
    const float* __restrict__ Wseg, const float* __restrict__ bseg,
    bf16_t* __restrict__ Wpe, bf16_t* __restrict__ Wqt,
    bf16_t* __restrict__ Wkv, bf16_t* __restrict__ Wot,
    bf16_t* __restrict__ Wsegt,
    float* __restrict__ bpe, float* __restrict__ bkv,
    float* __restrict__ bsegp, float* __restrict__ bqs)
{
    int n = blockIdx.x, k = threadIdx.x;
    if (n < 512) {
        const float* S = (n < 256) ? Wp : We;
        int nn = n & 255;
        Wpe[n * 256 + k] = (bf16_t)S[k * 256 + nn];
    } else if (n < 768) {
        int nn = n - 512;
        Wqt[nn * 256 + k] = (bf16_t)(Wq[k * 256 + nn] * QK_SCALE);
    } else if (n < 1280) {
        int m2 = n - 768;
        const float* S = (m2 < 256) ? Wk : Wv;
        int nn = m2 & 255;
        Wkv[m2 * 256 + k] = (bf16_t)S[k * 256 + nn];
    } else if (n < 1536) {
        int nn = n - 1280;
        Wot[nn * 256 + k] = (bf16_t)Wo[k * 256 + nn];
    } else if (n == 1536) {
        bpe[k] = bp[k]; bpe[256 + k] = be[k];
        bkv[k] = bk[k]; bkv[256 + k] = bv[k];
        bqs[k] = bq[k] * QK_SCALE;
        if (k < 32) bsegp[k] = (k < OUTC) ? bseg[k] : 0.f;
    } else {
        int n2 = n - 1537;   // 0..31
        Wsegt[n2 * 256 + k] = (n2 < OUTC) ? (bf16_t)Wseg[k * OUTC + n2] : (bf16_t)0.f;
    }
}

// ---- features fp32 -> bf16 copy (streaming, 8 elems/thread/iter) ----
__global__ __launch_bounds__(256) void k_cast(
    const float* __restrict__ in, bf16_t* __restrict__ out)
{
    const size_t total = (size_t)N_PTS * 32;   // groups of 8 floats
    const size_t stride = (size_t)gridDim.x * 256;
    for (size_t i = (size_t)blockIdx.x * 256 + threadIdx.x; i < total; i += stride) {
        float4 a = *(const float4*)(in + i * 8);
        float4 b = *(const float4*)(in + i * 8 + 4);
        bf16x8 o;
        o[0] = (bf16_t)a.x; o[1] = (bf16_t)a.y; o[2] = (bf16_t)a.z; o[3] = (bf16_t)a.w;
        o[4] = (bf16_t)b.x; o[5] = (bf16_t)b.y; o[6] = (bf16_t)b.z; o[7] = (bf16_t)b.w;
        *(bf16x8*)(out + i * 8) = o;
    }
}

// ---- CSR build: histogram -> scan -> placement ----
__global__ __launch_bounds__(256) void k_count(
    const int* __restrict__ indices, int* __restrict__ cnt_q, int* __restrict__ cnt_k,
    int* __restrict__ segq, int* __restrict__ segk)
{
    int i = blockIdx.x * 256 + threadIdx.x;
    if (i >= N_PTS) return;
    const int* id = indices + (size_t)i * 4;
    int b = id[0], z = id[1], y = id[2], x = id[3];
    int sq = ((b * Zd + (z >> 3)) * Yd + (y >> 3)) * Xd + (x >> 3);
    int sk = ((b * Ze + (z / 40)) * Ye + (y / 15)) * Xe + (x >> 4);
    segq[i] = sq; segk[i] = sk;
    atomicAdd(&cnt_q[sq], 1);
    atomicAdd(&cnt_k[sk], 1);
}

// single-block exclusive scan (wave shfl scan + cross-wave LDS)
__global__ __launch_bounds__(1024) void k_scan(
    const int* __restrict__ cnt, int n, int* __restrict__ offs, int* __restrict__ cursor)
{
    __shared__ int wbase[17];
    __shared__ int carry_s;
    const int t = threadIdx.x, lane = t & 63, w = t >> 6;
    if (t == 0) carry_s = 0;
    __syncthreads();
    for (int base = 0; base < n; base += 1024) {
        int v = (base + t < n) ? cnt[base + t] : 0;
        int incl = v;
        #pragma unroll
        for (int off = 1; off < 64; off <<= 1) {
            int u = __shfl_up(incl, off);
            if (lane >= off) incl += u;
        }
        if (lane == 63) wbase[w + 1] = incl;
        __syncthreads();
        if (t == 0) {
            int s = 0;
            wbase[0] = 0;
            #pragma unroll
            for (int i = 1; i <= 16; ++i) { s += wbase[i]; wbase[i] = s; }
        }
        __syncthreads();
        int excl = incl - v + wbase[w] + carry_s;
        if (base + t < n) { offs[base + t] = excl; cursor[base + t] = excl; }
        __syncthreads();
        if (t == 0) carry_s += wbase[16];
        __syncthreads();
    }
}

__global__ __launch_bounds__(256) void k_place(
    const int* __restrict__ segq, const int* __restrict__ segk,
    int* __restrict__ cur_q, int* __restrict__ cur_k,
    int* __restrict__ ids_q, int* __restrict__ ids_k)
{
    int i = blockIdx.x * 256 + threadIdx.x;
    if (i >= N_PTS) return;
    ids_q[atomicAdd(&cur_q[segq[i]], 1)] = i;
    ids_k[atomicAdd(&cur_k[segk[i]], 1)] = i;
}

// ---- fast MFMA GEMM, bf16 A: [M x 256] bf16 @ Wt[128-col tile x 256] bf16 ----
__global__ __launch_bounds__(256, 4) void k_gemm_bf(
    const bf16_t* __restrict__ A, int M,
    const bf16_t* __restrict__ Wt, const float* __restrict__ bias,
    bf16_t* __restrict__ outb, int ldo)
{
    __shared__ __align__(16) bf16_t Abuf[128 * 64];
    __shared__ __align__(16) bf16_t Bbuf[128 * 64];

    const int t = threadIdx.x;
    const int wave = t >> 6, lane = t & 63;
    const int wr = wave >> 1, wc = wave & 1;
    const int lrow = lane & 15, quad = lane >> 4;
    const int lr8 = lane >> 3, lc8 = lane & 7;
    const int row0 = blockIdx.y * 128;
    const int ntile = blockIdx.x;

    f32x4 acc[4][4];
    #pragma unroll
    for (int mi = 0; mi < 4; ++mi)
        #pragma unroll
        for (int ni = 0; ni < 4; ++ni)
            acc[mi][ni] = (f32x4){0.f, 0.f, 0.f, 0.f};

    for (int k0 = 0; k0 < 256; k0 += 64) {
        #pragma unroll
        for (int i = 0; i < 4; ++i) {
            int chunk = wave * 4 + i;
            int rowA = row0 + chunk * 8 + lr8;
            if (rowA > M - 1) rowA = M - 1;       // clamp, masked at write
            glds16(A + (size_t)rowA * 256 + k0 + lc8 * 8, &Abuf[chunk * 512]);
        }
        #pragma unroll
        for (int i = 0; i < 4; ++i) {
            int chunk = wave * 4 + i;
            glds16(Wt + (size_t)(ntile * 128 + chunk * 8 + lr8) * 256 + k0 + lc8 * 8,
                   &Bbuf[chunk * 512]);
        }
        asm volatile("s_waitcnt vmcnt(0)" ::: "memory");
        __builtin_amdgcn_sched_barrier(0);
        __syncthreads();

        #pragma unroll
        for (int kk = 0; kk < 64; kk += 32) {
            bf16x8 Af[4], Bf[4];
            #pragma unroll
            for (int mi = 0; mi < 4; ++mi)
                Af[mi] = *(const bf16x8*)&Abuf[(wr * 64 + mi * 16 + lrow) * 64 + kk + quad * 8];
            #pragma unroll
            for (int ni = 0; ni < 4; ++ni)
                Bf[ni] = *(const bf16x8*)&Bbuf[(wc * 64 + ni * 16 + lrow) * 64 + kk + quad * 8];
            #pragma unroll
            for (int mi = 0; mi < 4; ++mi)
                #pragma unroll
                for (int ni = 0; ni < 4; ++ni)
                    acc[mi][ni] = __builtin_amdgcn_mfma_f32_16x16x32_bf16(
                        Af[mi], Bf[ni], acc[mi][ni], 0, 0, 0);
        }
        __syncthreads();
    }

    const int colb = ntile * 128 + wc * 64;
    float biasv[4];
    #pragma unroll
    for (int ni = 0; ni < 4; ++ni) biasv[ni] = bias[colb + ni * 16 + lrow];

    #pragma unroll
    for (int mi = 0; mi < 4; ++mi) {
        int lr = wr * 64 + mi * 16 + quad * 4;
        #pragma unroll
        for (int reg = 0; reg < 4; ++reg) {
            int grow = row0 + lr + reg;
            if (grow >= M) continue;
            #pragma unroll
            for (int ni = 0; ni < 4; ++ni) {
                int col = colb + ni * 16 + lrow;
                outb[(size_t)grow * ldo + col] = (bf16_t)(acc[mi][ni][reg] + biasv[ni]);
            }
        }
    }
}

// ---- MFMA GEMM (fp32 A, VALU staging): mode 0 fp32 out; mode 2 bf16 out ----
__global__ __launch_bounds__(512, 2) void k_gemm(
    const float* __restrict__ A, int M,
    const bf16_t* __restrict__ Wt, const float* __restrict__ bias,
    int mode, float* __restrict__ outp, int ldo)
{
    __shared__ __align__(16) bf16_t Abuf[128][72];
    __shared__ __align__(16) bf16_t Bbuf[256][72];

    const int t = threadIdx.x;
    const int wave = t >> 6, lane = t & 63;
    const int wr = wave >> 2, wc = wave & 3;
    const int lrow = lane & 15, quad = lane >> 4;
    const int row0 = blockIdx.y * 128;
    const int ntile = blockIdx.x;

    f32x4 acc[4][4];
    #pragma unroll
    for (int mi = 0; mi < 4; ++mi)
        #pragma unroll
        for (int ni = 0; ni < 4; ++ni)
            acc[mi][ni] = (f32x4){0.f, 0.f, 0.f, 0.f};

    for (int k0 = 0; k0 < 256; k0 += 64) {
        #pragma unroll
        for (int i = 0; i < 4; ++i) {
            int c = i * 512 + t;
            int r = c >> 4, c4 = c & 15;
            float4 v = make_float4(0.f, 0.f, 0.f, 0.f);
            if (row0 + r < M)
                v = *(const float4*)(A + (size_t)(row0 + r) * 256 + k0 + c4 * 4);
            bf16x4 bv4;
            bv4[0] = (bf16_t)v.x; bv4[1] = (bf16_t)v.y;
            bv4[2] = (bf16_t)v.z; bv4[3] = (bf16_t)v.w;
            *(bf16x4*)&Abuf[r][c4 * 4] = bv4;
        }
        #pragma unroll
        for (int i = 0; i < 4; ++i) {
            int c = i * 512 + t;
            int r = c >> 3, c8 = c & 7;
            uint4 w = *(const uint4*)(Wt + ((size_t)(ntile * 256 + r)) * 256 + k0 + c8 * 8);
            *(uint4*)&Bbuf[r][c8 * 8] = w;
        }
        __syncthreads();

        #pragma unroll
        for (int kk = 0; kk < 64; kk += 32) {
            bf16x8 Af[4], Bf[4];
            #pragma unroll
            for (int mi = 0; mi < 4; ++mi)
                Af[mi] = *(const bf16x8*)&Abuf[wr * 64 + mi * 16 + lrow][kk + quad * 8];
            #pragma unroll
            for (int ni = 0; ni < 4; ++ni)
                Bf[ni] = *(const bf16x8*)&Bbuf[wc * 64 + ni * 16 + lrow][kk + quad * 8];
            #pragma unroll
            for (int mi = 0; mi < 4; ++mi)
                #pragma unroll
                for (int ni = 0; ni < 4; ++ni)
                    acc[mi][ni] = __builtin_amdgcn_mfma_f32_16x16x32_bf16(
                        Af[mi], Bf[ni], acc[mi][ni], 0, 0, 0);
        }
        __syncthreads();
    }

    const int colb = ntile * 256 + wc * 64;
    float biasv[4];
    #pragma unroll
    for (int ni = 0; ni < 4; ++ni) biasv[ni] = bias[colb + ni * 16 + lrow];

    if (mode == 0) {
        #pragma unroll
        for (int mi = 0; mi < 4; ++mi) {
            int lr = wr * 64 + mi * 16 + quad * 4;
            #pragma unroll
            for (int reg = 0; reg < 4; ++reg) {
                int grow = row0 + lr + reg;
                if (grow >= M) continue;
                #pragma unroll
                for (int ni = 0; ni < 4; ++ni) {
                    int col = colb + ni * 16 + lrow;
                    outp[(size_t)grow * ldo + col] = acc[mi][ni][reg] + biasv[ni];
                }
            }
        }
    } else {
        bf16_t* outb = (bf16_t*)outp;
        #pragma unroll
        for (int mi = 0; mi < 4; ++mi) {
            int lr = wr * 64 + mi * 16 + quad * 4;
            #pragma unroll
            for (int reg = 0; reg < 4; ++reg) {
                int grow = row0 + lr + reg;
                if (grow >= M) continue;
                #pragma unroll
                for (int ni = 0; ni < 4; ++ni) {
                    int col = colb + ni * 16 + lrow;
                    outb[(size_t)grow * ldo + col] = (bf16_t)(acc[mi][ni][reg] + biasv[ni]);
                }
            }
        }
    }
}

// ---- sine PE helper ----
__device__ inline float pe_val(int j, float cz, float cy, float cx) {
    if (j >= 252) return 0.f;
    int dim = j / 84;
    int f = j % 84;
    int fi = (f >= 42) ? (f - 42) : f;
    float c  = (dim == 0) ? cz : ((dim == 1) ? cy : cx);
    float sp = (dim == 0) ? 480.f : ((dim == 1) ? 360.f : 32.f);
    float cn = c / sp * 6.28318530717958647692f;
    float tt = expf((float)fi * (9.210340371976184f / 42.f));
    float ang = cn / tt;
    return (f >= 42) ? cosf(ang) : sinf(ang);
}

// ---- pool branch segment-max: one wave per segment (~5.6 pts/seg), PE fused ----
__global__ __launch_bounds__(256) void k_pool_q(
    const bf16_t* __restrict__ pfb, const int* __restrict__ ids,
    const int* __restrict__ offs, const int* __restrict__ cnt,
    float* __restrict__ out)
{
    const int t = threadIdx.x, lane = t & 63, w = t >> 6;
    const int s = blockIdx.x * 4 + w;
    if (s >= Sq) return;
    const int count = cnt[s], start = offs[s];
    float mx[4] = {-3.0e38f, -3.0e38f, -3.0e38f, -3.0e38f};
    for (int r = 0; r < count; ++r) {
        int i = ids[start + r];
        bf16x4 v = *(const bf16x4*)(pfb + (size_t)i * 256 + lane * 4);
        #pragma unroll
        for (int j = 0; j < 4; ++j) mx[j] = fmaxf(mx[j], (float)v[j]);
    }
    int rem = s % Gq;
    float cz = (float)((rem / (Yd * Xd)) * 8);
    float cy = (float)(((rem / Xd) % Yd) * 8);
    float cx = (float)((rem % Xd) * 8);
    #pragma unroll
    for (int j = 0; j < 4; ++j) {
        float v = (count > 0) ? mx[j] : 0.f;
        out[(size_t)s * 256 + lane * 4 + j] = v + pe_val(lane * 4 + j, cz, cy, cx);
    }
}

// ---- emb branch segment-max: one block (8 waves) per segment (~104 pts/seg) ----
__global__ __launch_bounds__(512) void k_pool_k(
    const bf16_t* __restrict__ efb, const int* __restrict__ ids,
    const int* __restrict__ offs, const int* __restrict__ cnt,
    float* __restrict__ out, int* __restrict__ kmask)
{
    __shared__ float red[8][256];
    const int t = threadIdx.x, lane = t & 63, w = t >> 6;
    const int s = blockIdx.x;
    const int count = cnt[s], start = offs[s];
    float mx[4] = {-3.0e38f, -3.0e38f, -3.0e38f, -3.0e38f};
    for (int r = w; r < count; r += 8) {
        int i = ids[start + r];
        bf16x4 v = *(const bf16x4*)(efb + (size_t)i * 256 + lane * 4);
        #pragma unroll
        for (int j = 0; j < 4; ++j) mx[j] = fmaxf(mx[j], (float)v[j]);
    }
    #pragma unroll
    for (int j = 0; j < 4; ++j) red[w][lane * 4 + j] = mx[j];
    __syncthreads();
    if (t < 256) {
        float m = red[0][t];
        #pragma unroll
        for (int i = 1; i < 8; ++i) m = fmaxf(m, red[i][t]);
        if (count == 0) m = 0.f;
        int rem = s % Gk;
        float cz = (float)((rem / (Ye * Xe)) * 40);
        float cy = (float)(((rem / Xe) % Ye) * 15);
        float cx = (float)((rem % Xe) * 16);
        out[(size_t)s * 256 + t] = m + pe_val(t, cz, cy, cx);
        if (t == 0) kmask[s] = (count > 0) ? 1 : 0;
    }
}

// ---- V transpose: VT[bh][d][g] = KVb[(b*Gk+g)*512 + 256 + h*32 + d] ----
__global__ __launch_bounds__(256) void k_vt(
    const bf16_t* __restrict__ KVb, bf16_t* __restrict__ VT)
{
    int idx = blockIdx.x * 256 + threadIdx.x;   // over 16*32*576 = 294912
    if (idx >= 16 * 32 * 576) return;
    int g = idx % 576;
    int d = (idx / 576) & 31;
    int bh = idx / (576 * 32);
    int b = bh >> 3, h = bh & 7;
    VT[idx] = KVb[((size_t)(b * Gk + g)) * 512 + 256 + h * 32 + d];
}

// ---- MFMA attention v5: single pass, NO max subtraction (scores bounded),
// exp2 with log2e folded into Q. K from global (L2), V+P in LDS.
// 768 thr (12 waves), 192 Q-rows/block, 6 chunks of 96 keys.
__global__ __launch_bounds__(768, 6) void k_attn5(
    const bf16_t* __restrict__ Q, const bf16_t* __restrict__ KV,
    const bf16_t* __restrict__ VT, const int* __restrict__ kmask,
    float* __restrict__ O)
{
    __shared__ __align__(16) bf16_t Vts[32][584];    // 37376 B
    __shared__ __align__(16) bf16_t Ps[12][16][104]; // 39936 B
    __shared__ float mskf[576];                      //  2304 B (total ~79.6 KB)

    const int bh = blockIdx.y;
    const int b = bh >> 3, h = bh & 7;
    const int t = threadIdx.x, wave = t >> 6, lane = t & 63;
    const int lrow = lane & 15, quad = lane >> 4;
    const int q0 = blockIdx.x * 192;

    // stage VT: 32 rows x 72 uint4 = 2304
    #pragma unroll
    for (int i = 0; i < 3; ++i) {
        int id = i * 768 + t;
        int d = id / 72, c8 = id % 72;
        uint4 v = *(const uint4*)(VT + (size_t)(bh * 32 + d) * 576 + c8 * 8);
        *(uint4*)&Vts[d][c8 * 8] = v;
    }
    if (t < 576)
        mskf[t] = kmask[b * Gk + t] ? 0.f : -1.0e9f;
    __syncthreads();

    // per-lane Q fragment (A operand)
    int qa = q0 + wave * 16 + lrow;
    if (qa > Gq - 1) qa = Gq - 1;
    const bf16x8 Aq = *(const bf16x8*)(Q + ((size_t)(b * Gq + qa)) * 256 + h * 32 + quad * 8);

    const bf16_t* Kbase = KV + ((size_t)b * Gk) * 512 + h * 32;

    f32x4 oacc[2];
    oacc[0] = (f32x4){0.f, 0.f, 0.f, 0.f};
    oacc[1] = (f32x4){0.f, 0.f, 0.f, 0.f};
    float l[4] = {0.f, 0.f, 0.f, 0.f};

    for (int c0 = 0; c0 < Gk; c0 += 96) {
        #pragma unroll
        for (int nt = 0; nt < 6; ++nt) {
            bf16x8 Bk = *(const bf16x8*)(Kbase + (size_t)(c0 + nt * 16 + lrow) * 512 + quad * 8);
            f32x4 sacc = __builtin_amdgcn_mfma_f32_16x16x32_bf16(
                Aq, Bk, (f32x4){0.f, 0.f, 0.f, 0.f}, 0, 0, 0);
            float pen = mskf[c0 + nt * 16 + lrow];
            #pragma unroll
            for (int r = 0; r < 4; ++r) {
                // scores pre-scaled by log2e: native exp2, no max needed
                float p = exp2f(sacc[r] + pen);
                l[r] += p;
                Ps[wave][quad * 4 + r][nt * 16 + lrow] = (bf16_t)p;
            }
        }
        #pragma unroll
        for (int ks = 0; ks < 3; ++ks) {
            bf16x8 Ap = *(const bf16x8*)&Ps[wave][lrow][ks * 32 + quad * 8];
            #pragma unroll
            for (int n2 = 0; n2 < 2; ++n2) {
                bf16x8 Bv = *(const bf16x8*)&Vts[n2 * 16 + lrow][c0 + ks * 32 + quad * 8];
                oacc[n2] = __builtin_amdgcn_mfma_f32_16x16x32_bf16(
                    Ap, Bv, oacc[n2], 0, 0, 0);
            }
        }
    }

    #pragma unroll
    for (int r = 0; r < 4; ++r)
        #pragma unroll
        for (int off = 1; off < 16; off <<= 1)
            l[r] += __shfl_xor(l[r], off);

    #pragma unroll
    for (int r = 0; r < 4; ++r) {
        int qi = q0 + wave * 16 + quad * 4 + r;
        if (qi >= Gq) continue;
        float inv = (l[r] > 0.f) ? (1.f / l[r]) : 0.f;
        #pragma unroll
        for (int n2 = 0; n2 < 2; ++n2)
            O[((size_t)(b * Gq + qi)) * 256 + h * 32 + n2 * 16 + lrow] = oacc[n2][r] * inv;
    }
}

// ---- residual + LayerNorm ----
__global__ __launch_bounds__(256) void k_ln(
    const float* __restrict__ oproj, const float* __restrict__ resid,
    const float* __restrict__ g, const float* __restrict__ bta,
    float* __restrict__ out)
{
    const int s = blockIdx.x, t = threadIdx.x;
    float h = resid[(size_t)s * D + t] + oproj[(size_t)s * D + t];

    float s1 = h, s2 = h * h;
    for (int o = 32; o > 0; o >>= 1) {
        s1 += __shfl_down(s1, o);
        s2 += __shfl_down(s2, o);
    }
    __shared__ float r1[4], r2[4];
    __shared__ float mu_s, rstd_s;
    int w = t >> 6;
    if ((t & 63) == 0) { r1[w] = s1; r2[w] = s2; }
    __syncthreads();
    if (t == 0) {
        float a = r1[0] + r1[1] + r1[2] + r1[3];
        float bsum = r2[0] + r2[1] + r2[2] + r2[3];
        float mu = a * (1.f / 256.f);
        float var = bsum * (1.f / 256.f) - mu * mu;
        mu_s = mu;
        rstd_s = rsqrtf(var + 1e-5f);
    }
    __syncthreads();
    out[(size_t)s * D + t] = (h - mu_s) * rstd_s * g[t] + bta[t];
}

// ---- final: vox = feat + mhca[seg_q]; logits = vox @ Wsegt^T + bseg via MFMA ----
__global__ __launch_bounds__(512, 2) void k_logits_mfma(
    const float* __restrict__ feat, const bf16_t* __restrict__ featb,
    const float* __restrict__ mhca,
    const int* __restrict__ indices, const bf16_t* __restrict__ Wsegt,
    const float* __restrict__ bsegp, float* __restrict__ out)
{
    __shared__ __align__(16) bf16_t Abuf[128][72];
    __shared__ __align__(16) bf16_t Bbuf[32][72];
    __shared__ int sq_s[128];

    const int t = threadIdx.x;
    const int wave = t >> 6, lane = t & 63;
    const int lrow = lane & 15, quad = lane >> 4;
    const int row0 = blockIdx.x * 128;

    if (t < 128) {
        int row = row0 + t;
        if (row < N_PTS) {
            const int* id = indices + (size_t)row * 4;
            sq_s[t] = ((id[0] * Zd + (id[1] >> 3)) * Yd + (id[2] >> 3)) * Xd + (id[3] >> 3);
        } else sq_s[t] = 0;
    }
    __syncthreads();

    f32x4 acc[2];
    acc[0] = (f32x4){0.f, 0.f, 0.f, 0.f};
    acc[1] = (f32x4){0.f, 0.f, 0.f, 0.f};

    for (int k0 = 0; k0 < 256; k0 += 64) {
        #pragma unroll
        for (int i = 0; i < 4; ++i) {
            int c = i * 512 + t;
            int r = c >> 4, c4 = c & 15;
            float4 v = make_float4(0.f, 0.f, 0.f, 0.f);
            int grow = row0 + r;
            if (grow < N_PTS) {
                float4 mm = *(const float4*)(mhca + (size_t)sq_s[r] * 256 + k0 + c4 * 4);
                if (featb) {
                    bf16x4 fv = *(const bf16x4*)(featb + (size_t)grow * 256 + k0 + c4 * 4);
                    v.x = (float)fv[0] + mm.x; v.y = (float)fv[1] + mm.y;
                    v.z = (float)fv[2] + mm.z; v.w = (float)fv[3] + mm.w;
                } else {
                    v = *(const float4*)(feat + (size_t)grow * 256 + k0 + c4 * 4);
                    v.x += mm.x; v.y += mm.y; v.z += mm.z; v.w += mm.w;
                }
            }
            bf16x4 bv4;
            bv4[0] = (bf16_t)v.x; bv4[1] = (bf16_t)v.y;
            bv4[2] = (bf16_t)v.z; bv4[3] = (bf16_t)v.w;
            *(bf16x4*)&Abuf[r][c4 * 4] = bv4;
        }
        if (t < 256) {
            int r = t >> 3, c8 = t & 7;
            uint4 w = *(const uint4*)(Wsegt + (size_t)r * 256 + k0 + c8 * 8);
            *(uint4*)&Bbuf[r][c8 * 8] = w;
        }
        __syncthreads();

        #pragma unroll
        for (int kk = 0; kk < 64; kk += 32) {
            bf16x8 Af = *(const bf16x8*)&Abuf[wave * 16 + lrow][kk + quad * 8];
            #pragma unroll
            for (int ni = 0; ni < 2; ++ni) {
                bf16x8 Bf = *(const bf16x8*)&Bbuf[ni * 16 + lrow][kk + quad * 8];
                acc[ni] = __builtin_amdgcn_mfma_f32_16x16x32_bf16(
                    Af, Bf, acc[ni], 0, 0, 0);
            }
        }
        __syncthreads();
    }

    #pragma unroll
    for (int ni = 0; ni < 2; ++ni) {
        int col = ni * 16 + lrow;
        if (col >= OUTC) continue;
        float bias = bsegp[col];
        #pragma unroll
        for (int reg = 0; reg < 4; ++reg) {
            int grow = row0 + wave * 16 + quad * 4 + reg;
            if (grow >= N_PTS) continue;
            out[(size_t)grow * OUTC + col] = acc[ni][reg] + bias;
        }
    }
}

extern "C" void kernel_launch(void* const* d_in, const int* in_sizes, int n_in,
                              void* d_out, int out_size, void* d_ws, size_t ws_size,
                              hipStream_t stream) {
    const float* features = (const float*)d_in[0];
    const float* W_pool = (const float*)d_in[1];
    const float* b_pool = (const float*)d_in[2];
    const float* W_emb  = (const float*)d_in[3];
    const float* b_emb  = (const float*)d_in[4];
    const float* Wq = (const float*)d_in[5];
    const float* bq = (const float*)d_in[6];
    const float* Wk = (const float*)d_in[7];
    const float* bk = (const float*)d_in[8];
    const float* Wv = (const float*)d_in[9];
    const float* bv = (const float*)d_in[10];
    const float* Wo = (const float*)d_in[11];
    const float* bo = (const float*)d_in[12];
    const float* ln_g = (const float*)d_in[13];
    const float* ln_b = (const float*)d_in[14];
    const float* W_seg = (const float*)d_in[15];
    const float* b_seg = (const float*)d_in[16];
    const int* indices = (const int*)d_in[17];
    float* out = (float*)d_out;

    float* ws = (float*)d_ws;
    const size_t SQD = (size_t)Sq * D;           // 5,529,600
    const size_t SKD = (size_t)Sk * D;           // 294,912
    const size_t PFB_FL = (size_t)N_PTS * D / 2; // 15,360,000 float slots (bf16 [N][256])

    // region P: pfb/efb (bf16) -> later Qb/KVb/attnO/oproj/mhca
    size_t oP   = 0;
    size_t oPF  = oP + PFB_FL;       // pool_feat fp32 [Sq][256]
    size_t oEF  = oPF + SQD;         // emb_feat fp32 [Sk][256]; later VT bf16 [16][32][576]
    size_t oWpe = oEF + SKD;         // 65536
    size_t oWqt = oWpe + 65536;      // 32768
    size_t oWkv = oWqt + 32768;      // 65536
    size_t oWot = oWkv + 65536;      // 32768
    size_t obpe = oWot + 32768;      // 512
    size_t obkv = obpe + 512;        // 512
    size_t oCnt = obkv + 512;        // cnt_q 21600 + cnt_k 1152 (zeroed)
    size_t oOffq = oCnt + 21600 + 1152;
    size_t oCurq = oOffq + 21600;
    size_t oOffk = oCurq + 21600;
    size_t oCurk = oOffk + 1152;
    size_t oSegq = oCurk + 1152;
    size_t oSegk = oSegq + N_PTS;
    size_t oIdsq = oSegk + N_PTS;
    size_t oIdsk = oIdsq + N_PTS;
    size_t oKm   = oIdsk + N_PTS;    // kmask 1152 ints
    size_t oWst  = oKm + 1152;       // Wsegt bf16 [32][256] = 4096 floats
    size_t obsg  = oWst + 4096;      // bsegp [32]
    size_t obqs  = obsg + 32;        // bqs [256] (scaled bq)
    size_t oFB   = obqs + 256;       // fb16 bf16 [N][256] (optional fast path)

    bf16_t* pfb = (bf16_t*)(ws + oP);
    float* pool_feat = ws + oPF;
    float* emb_feat  = ws + oEF;
    bf16_t* Wpe = (bf16_t*)(ws + oWpe);
    bf16_t* Wqt = (bf16_t*)(ws + oWqt);
    bf16_t* Wkv = (bf16_t*)(ws + oWkv);
    bf16_t* Wot = (bf16_t*)(ws + oWot);
    float* bpe = ws + obpe;
    float* bkv = ws + obkv;
    int* cnt_q = (int*)(ws + oCnt);
    int* cnt_k = cnt_q + 21600;
    int* offs_q = (int*)(ws + oOffq);
    int* cur_q  = (int*)(ws + oCurq);
    int* offs_k = (int*)(ws + oOffk);
    int* cur_k  = (int*)(ws + oCurk);
    int* segq = (int*)(ws + oSegq);
    int* segk = (int*)(ws + oSegk);
    int* ids_q = (int*)(ws + oIdsq);
    int* ids_k = (int*)(ws + oIdsk);
    int* kmask = (int*)(ws + oKm);
    bf16_t* Wsegt = (bf16_t*)(ws + oWst);
    float* bsegp = ws + obsg;
    float* bqs = ws + obqs;
    bf16_t* fb16 = (bf16_t*)(ws + oFB);

    // aliases inside region P (pfb dead after pooling kernels)
    bf16_t* Qb  = (bf16_t*)(ws + oP);
    bf16_t* KVb = (bf16_t*)(ws + oP + 2764800);
    float* attnO = ws + oP + 3059712;
    float* oproj = ws + oP + 8589312;
    float* mhca  = ws + oP + 3059712;   // reuses attnO slot after oproj gemm
    // VT reuses the emb_feat slot (emb_feat dead after the KV gemm)
    bf16_t* VT = (bf16_t*)(ws + oEF);

    const bool fast = ws_size >= (oFB + PFB_FL) * sizeof(float);

    // zero only the two histograms (~91 KB)
    hipMemsetAsync(cnt_q, 0, (21600 + 1152) * sizeof(int), stream);

    k_prep<<<1569, 256, 0, stream>>>(W_pool, W_emb, Wq, Wk, Wv, Wo,
                                     b_pool, b_emb, bq, bk, bv, W_seg, b_seg,
                                     Wpe, Wqt, Wkv, Wot, Wsegt, bpe, bkv, bsegp, bqs);

    if (fast)
        k_cast<<<2048, 256, 0, stream>>>(features, fb16);

    // CSR build
    k_count<<<(N_PTS + 255) / 256, 256, 0, stream>>>(indices, cnt_q, cnt_k, segq, segk);
    k_scan<<<1, 1024, 0, stream>>>(cnt_q, 21600, offs_q, cur_q);
    k_scan<<<1, 1024, 0, stream>>>(cnt_k, 1152, offs_k, cur_k);
    k_place<<<(N_PTS + 255) / 256, 256, 0, stream>>>(segq, segk, cur_q, cur_k, ids_q, ids_k);

    // --- emb branch: ef = features @ W_emb + b_emb (bf16), then gather-max ---
    if (fast) {
        dim3 g(2, (N_PTS + 127) / 128);
        k_gemm_bf<<<g, 256, 0, stream>>>(fb16, N_PTS, Wpe + 256 * 256, bpe + 256,
                                         pfb, 256);
    } else {
        dim3 g(1, (N_PTS + 127) / 128);
        k_gemm<<<g, 512, 0, stream>>>(features, N_PTS, Wpe + 256 * 256, bpe + 256, 2,
                                      (float*)pfb, 256);
    }
    k_pool_k<<<Sk, 512, 0, stream>>>(pfb, ids_k, offs_k, cnt_k, emb_feat, kmask);

    // --- pool branch: pf = features @ W_pool + b_pool (bf16), then gather-max ---
    if (fast) {
        dim3 g(2, (N_PTS + 127) / 128);
        k_gemm_bf<<<g, 256, 0, stream>>>(fb16, N_PTS, Wpe, bpe, pfb, 256);
    } else {
        dim3 g(1, (N_PTS + 127) / 128);
        k_gemm<<<g, 512, 0, stream>>>(features, N_PTS, Wpe, bpe, 2,
                                      (float*)pfb, 256);
    }
    k_pool_q<<<(Sq + 3) / 4, 256, 0, stream>>>(pfb, ids_q, offs_q, cnt_q, pool_feat);

    // Q = pool_feat @ (Wq*s*log2e) + bq*s*log2e  (bf16 out)
    {
        dim3 g(1, (Sq + 127) / 128);
        k_gemm<<<g, 512, 0, stream>>>(pool_feat, Sq, Wqt, bqs, 2, (float*)Qb, 256);
    }
    // KV = emb_feat @ [Wk|Wv] + [bk|bv], interleaved bf16 [Sk][512]
    {
        dim3 g(2, (Sk + 127) / 128);
        k_gemm<<<g, 512, 0, stream>>>(emb_feat, Sk, Wkv, bkv, 2, (float*)KVb, 512);
    }

    // V pre-transpose (emb_feat is dead now; VT aliases it)
    k_vt<<<(16 * 32 * 576 + 255) / 256, 256, 0, stream>>>(KVb, VT);

    {
        dim3 ag((Gq + 191) / 192, BATCH * NH);
        k_attn5<<<ag, 768, 0, stream>>>(Qb, KVb, VT, kmask, attnO);
    }

    // oproj = attnO @ Wo + bo (fp32 out)
    {
        dim3 g(1, (Sq + 127) / 128);
        k_gemm<<<g, 512, 0, stream>>>(attnO, Sq, Wot, bo, 0, oproj, 256);
    }

    k_ln<<<Sq, 256, 0, stream>>>(oproj, pool_feat, ln_g, ln_b, mhca);

    k_logits_mfma<<<(N_PTS + 127) / 128, 512, 0, stream>>>(
        features, fast ? fb16 : (const bf16_t*)nullptr, mhca, indices, Wsegt, bsegp, out);
}